// Round 2
// baseline (134.955 us; speedup 1.0000x reference)
//
#include <hip/hip_runtime.h>
#include <hip/hip_bf16.h>
#include <math.h>

// Problem dims (fixed by setup_inputs): B=64 samples, N=512 spins/flips, H=2048 hidden
constexpr int NB = 64;
constexpr int NN = 512;
constexpr int NH = 2048;
constexpr float LN2 = 0.6931471805599453f;

// Workspace layout (in floats)
constexpr size_t OFF_T2 = 0;                        // t2[k][h] = tanh(2W[k][h])      : 512*2048
constexpr size_t OFF_LC = OFF_T2 + (size_t)NN*NH;   // LC[k] = sum_h lncosh(2W[k][h]) : 512
constexpr size_t OFF_TT = OFF_LC + NN;              // Tt[h][b] = tanh(theta[b][h])   : 2048*64
constexpr size_t OFF_DS = OFF_TT + (size_t)NH*NB;   // dsum[hc][k][b] partial logs    : 8*512*64

// ============================ K1: fused prep (mixed-role blocks) ============
// blocks [0,512):   t2 row k + LC[k]
// blocks [512,640): full-K GEMM theta[b][h] = x@W + bias, then Tt[h][b]=tanh
__global__ __launch_bounds__(256) void k_prep(const float* __restrict__ W,
                                              const float* __restrict__ x,
                                              const float* __restrict__ bvec,
                                              float* __restrict__ t2,
                                              float* __restrict__ LC,
                                              float* __restrict__ Tt) {
    __shared__ float sm[4096];                 // 16 KB
    int bid = blockIdx.x, tid = threadIdx.x;
    if (bid < NN) {                            // ---- t2 / LC role ----
        int k = bid;
        float lsum = 0.f;
#pragma unroll
        for (int i = 0; i < 8; i++) {
            int h = tid + i * 256;
            float y  = 2.0f * W[(size_t)k * NH + h];
            float ay = fabsf(y);
            float e  = __expf(-2.0f * ay);
            float th = (1.0f - e) / (1.0f + e);
            t2[(size_t)k * NH + h] = copysignf(th, y);
            lsum += ay + __logf(1.0f + e) - LN2;   // lncosh(y)
        }
        sm[tid] = lsum; __syncthreads();
        for (int s = 128; s > 0; s >>= 1) {
            if (tid < s) sm[tid] += sm[tid + s];
            __syncthreads();
        }
        if (tid == 0) LC[k] = sm[0];
    } else {                                   // ---- GEMM + tanh role ----
        int gb = bid - NN;                     // 0..127
        int ht = gb & 31;                      // 32 h-tiles of 64
        int bt = gb >> 5;                      // 4 b-tiles of 16
        int hl = tid & 63, ns = tid >> 6;      // 4 n-segments of 128
        int h  = ht * 64 + hl;
        float acc[16];
#pragma unroll
        for (int j = 0; j < 16; j++) acc[j] = 0.f;
        const float* wp = W + h;
        const float* xp = x + (size_t)(bt * 16) * NN;   // wave-uniform rows -> s_load
        for (int n = ns * 128; n < ns * 128 + 128; n++) {
            float w = wp[(size_t)n * NH];
#pragma unroll
            for (int j = 0; j < 16; j++) acc[j] = fmaf(xp[(size_t)j * NN + n], w, acc[j]);
        }
        // reduce the 4 n-segments through LDS: sm[ns][hl][j]
#pragma unroll
        for (int j = 0; j < 16; j++) sm[ns * 1024 + hl * 16 + j] = acc[j];
        __syncthreads();
#pragma unroll
        for (int i = 0; i < 4; i++) {
            int idx = i * 256 + tid;           // 1024 outputs = (hl2, j2)
            int hl2 = idx >> 4, j2 = idx & 15;
            float th = bvec[ht * 64 + hl2];
#pragma unroll
            for (int s2 = 0; s2 < 4; s2++) th += sm[s2 * 1024 + idx];
            float ay = fabsf(th);
            float e  = __expf(-2.0f * ay);
            float t  = (1.0f - e) / (1.0f + e);
            Tt[(size_t)(ht * 64 + hl2) * NB + bt * 16 + j2] = copysignf(t, th);
        }
    }
}

// ============================ K2: main flip kernel ==========================
// lane<->b, wave covers 2 k's, block = 8 k's x 256 h-chunk; partial per-hc sums
__global__ __launch_bounds__(256) void k_main(const float* __restrict__ t2,
                                              const float* __restrict__ Tt,
                                              const float* __restrict__ x,
                                              float* __restrict__ dsum) {
    __shared__ float Tl[256 * NB];             // 64 KB slab: T[h0..h0+256)[all b]
    int tid = threadIdx.x;
    int kt  = blockIdx.x;                      // 64 k-tiles of 8
    int hc  = blockIdx.y;                      // 8 h-chunks of 256
    const float4* src = (const float4*)(Tt + (size_t)hc * 256 * NB);
    float4* dst = (float4*)Tl;
#pragma unroll
    for (int i = 0; i < 16; i++) dst[tid + i * 256] = src[tid + i * 256];
    __syncthreads();

    int wave = tid >> 6, lane = tid & 63;
    int k0 = __builtin_amdgcn_readfirstlane(kt * 8 + wave * 2);  // SGPR -> s_load t2 rows
    float ms0 = -x[(size_t)lane * NN + k0];    // -x[b][k0], L2-resident scattered read
    float ms1 = -x[(size_t)lane * NN + k0 + 1];
    const float* r0 = t2 + (size_t)k0 * NH + hc * 256;
    const float* r1 = r0 + NH;

    float lp0 = 0.f, lp1 = 0.f;
    for (int h0 = 0; h0 < 256; h0 += 32) {
        float p0 = 1.f, p1 = 1.f;
#pragma unroll
        for (int hh = 0; hh < 32; hh++) {
            int h = h0 + hh;
            float T = Tl[h * NB + lane];       // stride-1 over lanes: conflict-free
            p0 *= fmaf(r0[h] * T, ms0, 1.0f);  // u = 1 - s*T*tanh(2W)
            p1 *= fmaf(r1[h] * T, ms1, 1.0f);
        }
        lp0 += __logf(p0);                     // |ln u| small -> 32-chunk product safe
        lp1 += __logf(p1);
    }
    dsum[(size_t)hc * NN * NB + (size_t)k0 * NB + lane]       = lp0;   // own slice, plain store
    dsum[(size_t)hc * NN * NB + (size_t)(k0 + 1) * NB + lane] = lp1;
}

// ============================ K3: output reduction ==========================
__global__ void k_out(const float* __restrict__ dsum, const float* __restrict__ LC,
                      const float* __restrict__ x, const float* __restrict__ a,
                      const float* __restrict__ Oxy, float* __restrict__ out) {
    int b = blockIdx.x, tid = threadIdx.x;
    float sum = 0.f;
    for (int k = tid; k < NN; k += 256) {
        float d = LC[k] - 2.0f * x[(size_t)b * NN + k] * a[k];
#pragma unroll
        for (int hc = 0; hc < 8; hc++) d += dsum[(size_t)hc * NN * NB + (size_t)k * NB + b];
        sum += Oxy[k] * __expf(d);
    }
    __shared__ float red[256];
    red[tid] = sum; __syncthreads();
    for (int st = 128; st > 0; st >>= 1) {
        if (tid < st) red[tid] += red[tid + st];
        __syncthreads();
    }
    if (tid == 0) out[b] = red[0];
}

extern "C" void kernel_launch(void* const* d_in, const int* in_sizes, int n_in,
                              void* d_out, int out_size, void* d_ws, size_t ws_size,
                              hipStream_t stream) {
    const float* x    = (const float*)d_in[0];
    const float* W    = (const float*)d_in[1];
    const float* bvec = (const float*)d_in[2];
    const float* a    = (const float*)d_in[3];
    const float* Oxy  = (const float*)d_in[4];
    float* out = (float*)d_out;

    float* ws   = (float*)d_ws;
    float* t2   = ws + OFF_T2;
    float* LC   = ws + OFF_LC;
    float* Tt   = ws + OFF_TT;
    float* dsum = ws + OFF_DS;

    k_prep<<<NN + 128, 256, 0, stream>>>(W, x, bvec, t2, LC, Tt);
    k_main<<<dim3(NN / 8, NH / 256), 256, 0, stream>>>(t2, Tt, x, dsum);
    k_out<<<NB, 256, 0, stream>>>(dsum, LC, x, a, Oxy, out);
}

// Round 3
// 94.111 us; speedup vs baseline: 1.4340x; 1.4340x over previous
//
#include <hip/hip_runtime.h>
#include <hip/hip_bf16.h>
#include <math.h>

// Problem dims (fixed by setup_inputs): B=64 samples, N=512 spins/flips, H=2048 hidden
constexpr int NB = 64;
constexpr int NN = 512;
constexpr int NH = 2048;
constexpr float LN2 = 0.6931471805599453f;

// Workspace layout (floats)
constexpr size_t OFF_T2  = 0;                         // t2[k][h]=tanh(2W)        : 512*2048
constexpr size_t OFF_LC  = OFF_T2  + (size_t)NN*NH;   // LC[k]=sum lncosh(2W)     : 512
constexpr size_t OFF_XT  = OFF_LC  + NN;              // xt[n][b]=x[b][n]         : 512*64
constexpr size_t OFF_TT  = OFF_XT  + (size_t)NN*NB;   // Tt[h][b]=tanh(theta)     : 2048*64
constexpr size_t OFF_THP = OFF_TT  + (size_t)NH*NB;   // thp[nc][b][h] partials   : 16*64*2048
constexpr size_t OFF_DS  = OFF_THP + (size_t)16*NB*NH;// dsum[hc][k][b]           : 8*512*64

// ===== K1: mixed: blocks [0,512) t2/LC row k (float4-vectorized); [512,520) xt transpose
__global__ __launch_bounds__(256) void k_pre(const float* __restrict__ W,
                                             const float* __restrict__ x,
                                             float* __restrict__ t2,
                                             float* __restrict__ LC,
                                             float* __restrict__ xt) {
    int bid = blockIdx.x, tid = threadIdx.x;
    if (bid < NN) {
        int k = bid;
        const float4* wr = (const float4*)(W + (size_t)k * NH);
        float4* tr = (float4*)(t2 + (size_t)k * NH);
        float4 w0 = wr[tid], w1 = wr[tid + 256];   // both loads in flight up-front
        float in[8] = {w0.x, w0.y, w0.z, w0.w, w1.x, w1.y, w1.z, w1.w};
        float t[8], lsum = 0.f;
#pragma unroll
        for (int i = 0; i < 8; i++) {
            float y  = 2.0f * in[i];
            float ay = fabsf(y);
            float e  = __expf(-2.0f * ay);
            t[i] = copysignf((1.0f - e) / (1.0f + e), y);
            lsum += ay + __logf(1.0f + e) - LN2;   // lncosh(y)
        }
        tr[tid]       = make_float4(t[0], t[1], t[2], t[3]);
        tr[tid + 256] = make_float4(t[4], t[5], t[6], t[7]);
        __shared__ float red[256];
        red[tid] = lsum; __syncthreads();
        for (int s = 128; s > 0; s >>= 1) {
            if (tid < s) red[tid] += red[tid + s];
            __syncthreads();
        }
        if (tid == 0) LC[k] = red[0];
    } else {                                        // xt transpose: 8 blocks x 256 x 16
        int base = (bid - NN) * 4096;
#pragma unroll
        for (int i = 0; i < 16; i++) {
            int tIdx = base + i * 256 + tid;        // tIdx = n*64 + b
            int b = tIdx & 63, n = tIdx >> 6;
            xt[tIdx] = x[(size_t)b * NN + n];
        }
    }
}

// ===== K2: split-K GEMM partials thp[nc][b][h] = sum_{n in chunk of 32} x[b][n] W[n][h]
__global__ __launch_bounds__(256) void k_gemm(const float* __restrict__ W,
                                              const float* __restrict__ xt,
                                              float* __restrict__ thp) {
    int tid = threadIdx.x;
    int h  = blockIdx.x * 256 + tid;   // 8 h-tiles
    int bt = blockIdx.y;               // 4 b-tiles of 16
    int nc = blockIdx.z;               // 16 n-chunks of 32
    float acc[16];
#pragma unroll
    for (int j = 0; j < 16; j++) acc[j] = 0.f;
    const float* xp = xt + (size_t)nc * 32 * NB + bt * 16;  // uniform, j-contig -> s_load_dwordx16
    const float* wp = W + (size_t)(nc * 32) * NH + h;
#pragma unroll 4
    for (int n = 0; n < 32; n++) {
        float w = wp[(size_t)n * NH];
#pragma unroll
        for (int j = 0; j < 16; j++) acc[j] = fmaf(xp[n * NB + j], w, acc[j]);
    }
    float* op = thp + (size_t)nc * NB * NH + (size_t)(bt * 16) * NH + h;
#pragma unroll
    for (int j = 0; j < 16; j++) op[(size_t)j * NH] = acc[j];
}

// ===== K3: theta = bias + sum of 16 partials; Tt[h][b] = tanh(theta)
__global__ __launch_bounds__(256) void k_tanh(const float* __restrict__ thp,
                                              const float* __restrict__ bvec,
                                              float* __restrict__ Tt) {
    int g = blockIdx.x * 256 + threadIdx.x;   // 131072 = b*2048 + h
    int h = g & (NH - 1), b = g >> 11;
    float th = bvec[h];
#pragma unroll
    for (int nc = 0; nc < 16; nc++) th += thp[(size_t)nc * NB * NH + g];
    float ay = fabsf(th);
    float e  = __expf(-2.0f * ay);
    Tt[(size_t)h * NB + b] = copysignf((1.0f - e) / (1.0f + e), th);
}

// ===== K4: main flip kernel. lane<->b, wave covers 2 k's, block = 8 k x 256 h-chunk
__global__ __launch_bounds__(256) void k_main(const float* __restrict__ t2,
                                              const float* __restrict__ Tt,
                                              const float* __restrict__ xt,
                                              float* __restrict__ dsum) {
    __shared__ float Tl[256 * NB];             // 64 KB slab: T[h0..h0+256)[all b]
    int tid = threadIdx.x;
    int kt  = blockIdx.x;                      // 64 k-tiles of 8
    int hc  = blockIdx.y;                      // 8 h-chunks of 256
    const float4* src = (const float4*)(Tt + (size_t)hc * 256 * NB);
    float4* dst = (float4*)Tl;
#pragma unroll
    for (int i = 0; i < 16; i++) dst[tid + i * 256] = src[tid + i * 256];
    __syncthreads();

    int wave = tid >> 6, lane = tid & 63;
    int k0 = __builtin_amdgcn_readfirstlane(kt * 8 + wave * 2);  // SGPR -> scalar t2 rows
    float ms0 = -xt[(size_t)k0 * NB + lane];       // coalesced from xt
    float ms1 = -xt[(size_t)(k0 + 1) * NB + lane];
    const float* r0 = t2 + (size_t)k0 * NH + hc * 256;
    const float* r1 = r0 + NH;

    float lp0 = 0.f, lp1 = 0.f;
    for (int h0 = 0; h0 < 256; h0 += 32) {
        float p0 = 1.f, p1 = 1.f;
#pragma unroll
        for (int hh = 0; hh < 32; hh++) {
            int h = h0 + hh;
            float T = Tl[h * NB + lane];       // stride-1 over lanes: conflict-free
            p0 *= fmaf(r0[h] * T, ms0, 1.0f);  // u = 1 - s*T*tanh(2W)
            p1 *= fmaf(r1[h] * T, ms1, 1.0f);
        }
        lp0 += __logf(p0);                     // |ln u| small -> 32-chunk product safe
        lp1 += __logf(p1);
    }
    dsum[(size_t)hc * NN * NB + (size_t)k0 * NB + lane]       = lp0;  // own slice, plain store
    dsum[(size_t)hc * NN * NB + (size_t)(k0 + 1) * NB + lane] = lp1;
}

// ===== K5: out[b] = sum_k Oxy[k] * exp(sum_hc dsum + LC[k] - 2 x[b][k] a[k])
__global__ void k_out(const float* __restrict__ dsum, const float* __restrict__ LC,
                      const float* __restrict__ xt, const float* __restrict__ a,
                      const float* __restrict__ Oxy, float* __restrict__ out) {
    int b = blockIdx.x, tid = threadIdx.x;
    float sum = 0.f;
    for (int k = tid; k < NN; k += 256) {
        float d = LC[k] - 2.0f * xt[(size_t)k * NB + b] * a[k];
#pragma unroll
        for (int hc = 0; hc < 8; hc++) d += dsum[(size_t)hc * NN * NB + (size_t)k * NB + b];
        sum += Oxy[k] * __expf(d);
    }
    __shared__ float red[256];
    red[tid] = sum; __syncthreads();
    for (int st = 128; st > 0; st >>= 1) {
        if (tid < st) red[tid] += red[tid + st];
        __syncthreads();
    }
    if (tid == 0) out[b] = red[0];
}

extern "C" void kernel_launch(void* const* d_in, const int* in_sizes, int n_in,
                              void* d_out, int out_size, void* d_ws, size_t ws_size,
                              hipStream_t stream) {
    const float* x    = (const float*)d_in[0];
    const float* W    = (const float*)d_in[1];
    const float* bvec = (const float*)d_in[2];
    const float* a    = (const float*)d_in[3];
    const float* Oxy  = (const float*)d_in[4];
    float* out = (float*)d_out;

    float* ws   = (float*)d_ws;
    float* t2   = ws + OFF_T2;
    float* LC   = ws + OFF_LC;
    float* xt   = ws + OFF_XT;
    float* Tt   = ws + OFF_TT;
    float* thp  = ws + OFF_THP;
    float* dsum = ws + OFF_DS;

    k_pre<<<NN + 8, 256, 0, stream>>>(W, x, t2, LC, xt);
    k_gemm<<<dim3(NH / 256, NB / 16, 16), 256, 0, stream>>>(W, xt, thp);
    k_tanh<<<NB * NH / 256, 256, 0, stream>>>(thp, bvec, Tt);
    k_main<<<dim3(NN / 8, NH / 256), 256, 0, stream>>>(t2, Tt, xt, dsum);
    k_out<<<NB, 256, 0, stream>>>(dsum, LC, xt, a, Oxy, out);
}